// Round 4
// baseline (152.842 us; speedup 1.0000x reference)
//
#include <hip/hip_runtime.h>
#include <hip/hip_bf16.h>

#define NB 2048     // batch rows
#define NL 64       // latent dim
#define NN 16       // nuisance dim
#define NROW 80     // NL + NN
#define NO 2048     // output dim
#define TPB 256     // threads per block
#define OPT 8       // cols per thread (2048/256)
#define RPB 8       // rows per block (pass 2)
#define LCH 8       // l-chunk staged in LDS
#define MAXG (NB / RPB + NN)   // 272 max groups

typedef unsigned int   u32;
typedef unsigned short u16;

struct Group { int id; int start; int nr; int pad; };

__device__ __forceinline__ float bflo(u32 u) { union { u32 i; float f; } c; c.i = u << 16;         return c.f; }
__device__ __forceinline__ float bfhi(u32 u) { union { u32 i; float f; } c; c.i = u & 0xffff0000u; return c.f; }
__device__ __forceinline__ u16 f2bf(float f) { __hip_bfloat16 h = __float2bfloat16(f); return *(u16*)&h; }

// ---- Pass 0: bucket rows by argmax id, build group table, emit theta ----
__global__ __launch_bounds__(TPB) void bucket_rows(
    const float* __restrict__ z, const float* __restrict__ pxr,
    int* __restrict__ perm, Group* __restrict__ groups, int* __restrict__ n_groups,
    float* __restrict__ out)
{
    __shared__ int cnt[NN], start[NN], cur[NN];
    const int tid = threadIdx.x;
    if (tid < NN) cnt[tid] = 0;
    for (int o = tid; o < NO; o += TPB)            // theta = exp(px_r)
        out[(size_t)NB * NO + o] = __expf(pxr[o]);
    __syncthreads();

    int ids[NB / TPB];
    #pragma unroll
    for (int k = 0; k < NB / TPB; ++k) {
        const int row = tid + k * TPB;
        const float* p = z + (size_t)row * NROW + NL;
        float best = p[0]; int bi = 0;
        #pragma unroll
        for (int i = 1; i < NN; ++i) { float v = p[i]; if (v > best) { best = v; bi = i; } }  // strict > = numpy first-max
        ids[k] = bi;
        atomicAdd(&cnt[bi], 1);
    }
    __syncthreads();
    if (tid == 0) {
        int acc = 0;
        for (int i = 0; i < NN; ++i) { start[i] = acc; cur[i] = acc; acc += cnt[i]; }
    }
    __syncthreads();
    #pragma unroll
    for (int k = 0; k < NB / TPB; ++k) {
        const int row = tid + k * TPB;
        const int pos = atomicAdd(&cur[ids[k]], 1);
        perm[pos] = row;
    }
    __syncthreads();
    if (tid == 0) {
        int g = 0;
        for (int i = 0; i < NN; ++i) {
            for (int off = 0; off < cnt[i]; off += RPB) {
                groups[g].id = i; groups[g].start = start[i] + off;
                groups[g].nr = min(RPB, cnt[i] - off); groups[g].pad = 0; ++g;
            }
        }
        *n_groups = g;
    }
}

// ---- Pass 1: M[id][l][o] = bf16(W[l][o] + A[id][l][o]) ----
__global__ __launch_bounds__(TPB) void build_m(const float* __restrict__ W,
                                               const float* __restrict__ A,
                                               u16* __restrict__ M) {
    size_t t    = (size_t)blockIdx.x * TPB + threadIdx.x;
    size_t base = t * 4;
    float4 w = *(const float4*)(W + (base & (size_t)(NL * NO - 1)));
    float4 a = *(const float4*)(A + base);
    ushort4 m;
    m.x = f2bf(w.x + a.x); m.y = f2bf(w.y + a.y);
    m.z = f2bf(w.z + a.z); m.w = f2bf(w.w + a.w);
    *(ushort4*)(M + base) = m;
}

// ---- Pass 2: id-grouped GEMM + softmax. 8 rows/block, M[id] staged via LDS ----
__global__ __launch_bounds__(TPB) void decoder_g(
    const float* __restrict__ z, const float* __restrict__ sf,
    const u16* __restrict__ M, const float* __restrict__ offs,
    const int* __restrict__ perm, const Group* __restrict__ groups,
    const int* __restrict__ n_groups, float* __restrict__ out)
{
    const int tid = threadIdx.x;
    const int g   = blockIdx.x;
    if (g >= *n_groups) return;
    const int id     = groups[g].id;
    const int pstart = groups[g].start;
    const int nr     = groups[g].nr;

    __shared__ int   rows_s[RPB];
    __shared__ float zT[NL][RPB];        // [l][r]
    __shared__ u16   Ml[LCH * NO];       // 32 KB staged M chunk
    __shared__ float red[2][4][RPB];

    if (tid < RPB) rows_s[tid] = perm[pstart + (tid < nr ? tid : 0)];
    __syncthreads();

    {   // load zT (coalesced: 64 consecutive floats per row segment)
        const int l = tid & 63, r0 = tid >> 6;           // r0 in 0..3
        zT[l][r0]     = z[(size_t)rows_s[r0]     * NROW + l];
        zT[l][r0 + 4] = z[(size_t)rows_s[r0 + 4] * NROW + l];
    }

    const int o0 = tid * OPT;
    float acc[RPB][OPT];
    {
        float4 oa = *(const float4*)(offs + id * NO + o0);
        float4 ob = *(const float4*)(offs + id * NO + o0 + 4);
        float offv[OPT] = { oa.x, oa.y, oa.z, oa.w, ob.x, ob.y, ob.z, ob.w };
        #pragma unroll
        for (int r = 0; r < RPB; ++r)
            #pragma unroll
            for (int c = 0; c < OPT; ++c) acc[r][c] = offv[c];
    }

    const uint4* Mg  = (const uint4*)(M + (size_t)id * NL * NO);   // uint4 = 8 bf16
    uint4*       Mlv = (uint4*)Ml;

    for (int ch = 0; ch < NL / LCH; ++ch) {
        __syncthreads();   // also covers zT on first iter
        const uint4* src = Mg + ch * LCH * (NO / 8);
        #pragma unroll
        for (int j = 0; j < (LCH * NO / 8) / TPB; ++j)    // 8 uint4 per thread
            Mlv[j * TPB + tid] = src[j * TPB + tid];
        __syncthreads();
        #pragma unroll
        for (int l = 0; l < LCH; ++l) {
            uint4 m = *(const uint4*)(Ml + l * NO + o0);
            float v[OPT] = { bflo(m.x), bfhi(m.x), bflo(m.y), bfhi(m.y),
                             bflo(m.z), bfhi(m.z), bflo(m.w), bfhi(m.w) };
            const int gl = ch * LCH + l;
            #pragma unroll
            for (int r = 0; r < RPB; ++r) {
                const float zl = zT[gl][r];
                #pragma unroll
                for (int c = 0; c < OPT; ++c) acc[r][c] += zl * v[c];
            }
        }
    }

    // ---- 8 parallel block softmaxes ----
    #pragma unroll
    for (int r = 0; r < RPB; ++r) {
        float m = acc[r][0];
        #pragma unroll
        for (int c = 1; c < OPT; ++c) m = fmaxf(m, acc[r][c]);
        #pragma unroll
        for (int off = 32; off > 0; off >>= 1) m = fmaxf(m, __shfl_down(m, off));
        if ((tid & 63) == 0) red[0][tid >> 6][r] = m;
    }
    __syncthreads();
    if (tid < RPB)
        red[0][0][tid] = fmaxf(fmaxf(red[0][0][tid], red[0][1][tid]),
                               fmaxf(red[0][2][tid], red[0][3][tid]));
    __syncthreads();

    #pragma unroll
    for (int r = 0; r < RPB; ++r) {
        const float mxr = red[0][0][r];
        float s = 0.f;
        #pragma unroll
        for (int c = 0; c < OPT; ++c) { acc[r][c] = __expf(acc[r][c] - mxr); s += acc[r][c]; }
        #pragma unroll
        for (int off = 32; off > 0; off >>= 1) s += __shfl_down(s, off);
        if ((tid & 63) == 0) red[1][tid >> 6][r] = s;
    }
    __syncthreads();
    if (tid < RPB)
        red[1][0][tid] = (red[1][0][tid] + red[1][1][tid]) + (red[1][2][tid] + red[1][3][tid]);
    __syncthreads();

    for (int r = 0; r < nr; ++r) {
        const float scl = sf[rows_s[r]] / red[1][0][r];
        float* op = out + (size_t)rows_s[r] * NO + o0;
        *(float4*)(op)     = make_float4(acc[r][0] * scl, acc[r][1] * scl, acc[r][2] * scl, acc[r][3] * scl);
        *(float4*)(op + 4) = make_float4(acc[r][4] * scl, acc[r][5] * scl, acc[r][6] * scl, acc[r][7] * scl);
    }
}

// ---- Fallback (ws too small): round-3 row-per-block fp32 path ----
__global__ __launch_bounds__(TPB) void decoder_f(
    const float* __restrict__ z, const float* __restrict__ sf,
    const float* __restrict__ W, const float* __restrict__ A,
    const float* __restrict__ offs, const float* __restrict__ pxr,
    float* __restrict__ out)
{
    const int b   = blockIdx.x;
    const int tid = threadIdx.x;
    if (b == NB) {
        for (int o = tid; o < NO; o += TPB) out[(size_t)NB * NO + o] = __expf(pxr[o]);
        return;
    }
    __shared__ float z0s[NL];
    __shared__ int   s_id;
    __shared__ float s_red[6];
    if (tid < NL) z0s[tid] = z[b * NROW + tid];
    if (tid == 0) {
        float best = -1e30f; int bi = 0;
        for (int i = 0; i < NN; ++i) { float v = z[b * NROW + NL + i]; if (v > best) { best = v; bi = i; } }
        s_id = bi;
    }
    __syncthreads();
    const int id = s_id;
    const int o0 = tid * OPT;
    const float* wp = W + o0;
    const float* ap = A + (size_t)id * NL * NO + o0;
    float acc[OPT];
    {
        float4 oa = *(const float4*)(offs + id * NO + o0);
        float4 ob = *(const float4*)(offs + id * NO + o0 + 4);
        acc[0]=oa.x; acc[1]=oa.y; acc[2]=oa.z; acc[3]=oa.w;
        acc[4]=ob.x; acc[5]=ob.y; acc[6]=ob.z; acc[7]=ob.w;
    }
    #pragma unroll 4
    for (int l = 0; l < NL; ++l) {
        const float zl = z0s[l];
        float4 w0 = *(const float4*)(wp + l * NO);
        float4 w1 = *(const float4*)(wp + l * NO + 4);
        float4 a0 = *(const float4*)(ap + l * NO);
        float4 a1 = *(const float4*)(ap + l * NO + 4);
        acc[0] += zl * (w0.x + a0.x); acc[1] += zl * (w0.y + a0.y);
        acc[2] += zl * (w0.z + a0.z); acc[3] += zl * (w0.w + a0.w);
        acc[4] += zl * (w1.x + a1.x); acc[5] += zl * (w1.y + a1.y);
        acc[6] += zl * (w1.z + a1.z); acc[7] += zl * (w1.w + a1.w);
    }
    float m = acc[0];
    #pragma unroll
    for (int j = 1; j < OPT; ++j) m = fmaxf(m, acc[j]);
    #pragma unroll
    for (int off = 32; off > 0; off >>= 1) m = fmaxf(m, __shfl_down(m, off));
    if ((tid & 63) == 0) s_red[tid >> 6] = m;
    __syncthreads();
    if (tid == 0) s_red[4] = fmaxf(fmaxf(s_red[0], s_red[1]), fmaxf(s_red[2], s_red[3]));
    __syncthreads();
    const float mx = s_red[4];
    float ex[OPT];
    float s = 0.f;
    #pragma unroll
    for (int j = 0; j < OPT; ++j) { ex[j] = __expf(acc[j] - mx); s += ex[j]; }
    #pragma unroll
    for (int off = 32; off > 0; off >>= 1) s += __shfl_down(s, off);
    if ((tid & 63) == 0) s_red[tid >> 6] = s;
    __syncthreads();
    if (tid == 0) s_red[5] = (s_red[0] + s_red[1]) + (s_red[2] + s_red[3]);
    __syncthreads();
    const float scale = sf[b] / s_red[5];
    float* op = out + (size_t)b * NO + o0;
    *(float4*)(op)     = make_float4(ex[0]*scale, ex[1]*scale, ex[2]*scale, ex[3]*scale);
    *(float4*)(op + 4) = make_float4(ex[4]*scale, ex[5]*scale, ex[6]*scale, ex[7]*scale);
}

extern "C" void kernel_launch(void* const* d_in, const int* in_sizes, int n_in,
                              void* d_out, int out_size, void* d_ws, size_t ws_size,
                              hipStream_t stream) {
    const float* z    = (const float*)d_in[0];
    const float* sf   = (const float*)d_in[1];
    const float* W    = (const float*)d_in[2];
    const float* A    = (const float*)d_in[3];
    const float* offs = (const float*)d_in[4];
    const float* pxr  = (const float*)d_in[5];
    float* out = (float*)d_out;

    const size_t m_bytes  = (size_t)NN * NL * NO * sizeof(u16);  // 4 MiB
    const size_t ws_need  = m_bytes + 8192 + 8192 + 256;
    if (ws_size >= ws_need) {
        char* wsb = (char*)d_ws;
        u16*   M       = (u16*)wsb;
        int*   perm    = (int*)(wsb + m_bytes);
        Group* groups  = (Group*)(wsb + m_bytes + 8192);
        int*   ngroups = (int*)(wsb + m_bytes + 8192 + 8192);
        hipLaunchKernelGGL(bucket_rows, dim3(1), dim3(TPB), 0, stream, z, pxr, perm, groups, ngroups, out);
        hipLaunchKernelGGL(build_m, dim3((NN * NL * NO / 4) / TPB), dim3(TPB), 0, stream, W, A, M);
        hipLaunchKernelGGL(decoder_g, dim3(MAXG), dim3(TPB), 0, stream, z, sf, M, offs, perm, groups, ngroups, out);
    } else {
        hipLaunchKernelGGL(decoder_f, dim3(NB + 1), dim3(TPB), 0, stream, z, sf, W, A, offs, pxr, out);
    }
}

// Round 5
// 118.506 us; speedup vs baseline: 1.2897x; 1.2897x over previous
//
#include <hip/hip_runtime.h>
#include <hip/hip_bf16.h>

#define NB 2048     // batch rows
#define NL 64       // latent dim
#define NN 16       // nuisance dim
#define NROW 80     // NL + NN
#define NO 2048     // output dim
#define RPB 8       // rows per group
#define MAXG (NB / RPB + NN)   // 272 max groups
#define CTILE 512   // cols per gemm block
#define NCT (NO / CTILE)       // 4 col tiles

typedef unsigned int   u32;
typedef unsigned short u16;

struct Group { int id; int start; int nr; int pad; };

__device__ __forceinline__ float bflo(u32 u) { union { u32 i; float f; } c; c.i = u << 16;         return c.f; }
__device__ __forceinline__ float bfhi(u32 u) { union { u32 i; float f; } c; c.i = u & 0xffff0000u; return c.f; }
__device__ __forceinline__ u16 f2bf(float f) { __hip_bfloat16 h = __float2bfloat16(f); return *(u16*)&h; }

// ---- Pass 0: one 1024-thread block: argmax ids, bucket-sort perm, group table, theta ----
__global__ __launch_bounds__(1024) void bucket_all(
    const float* __restrict__ z, const float* __restrict__ pxr,
    int* __restrict__ perm, Group* __restrict__ groups, int* __restrict__ ngroups,
    float* __restrict__ out)
{
    __shared__ int cnt[NN], start_s[NN], cur[NN], gbase[NN];
    const int tid = threadIdx.x;
    if (tid < NN) cnt[tid] = 0;
    for (int o = tid; o < NO; o += 1024)                 // theta = exp(px_r)
        out[(size_t)NB * NO + o] = __expf(pxr[o]);
    __syncthreads();

    int myid[NB / 1024];
    #pragma unroll
    for (int k = 0; k < NB / 1024; ++k) {
        const int row = tid + k * 1024;
        const float* p = z + (size_t)row * NROW + NL;
        float best = p[0]; int bi = 0;
        #pragma unroll
        for (int i = 1; i < NN; ++i) { float v = p[i]; if (v > best) { best = v; bi = i; } }  // strict > = numpy first-max
        myid[k] = bi;
        atomicAdd(&cnt[bi], 1);
    }
    __syncthreads();
    if (tid == 0) {
        int acc = 0, g = 0;
        for (int i = 0; i < NN; ++i) {
            start_s[i] = acc; cur[i] = acc; gbase[i] = g;
            acc += cnt[i]; g += (cnt[i] + RPB - 1) / RPB;
        }
        *ngroups = g;
    }
    __syncthreads();
    #pragma unroll
    for (int k = 0; k < NB / 1024; ++k) {
        const int row = tid + k * 1024;
        const int pos = atomicAdd(&cur[myid[k]], 1);
        perm[pos] = row;
    }
    if (tid < NN) {
        const int c = cnt[tid], s = start_s[tid], gb = gbase[tid];
        for (int j = 0; j * RPB < c; ++j) {
            Group gr; gr.id = tid; gr.start = s + j * RPB;
            gr.nr = min(RPB, c - j * RPB); gr.pad = 0;
            groups[gb + j] = gr;
        }
    }
}

// ---- Pass 1: M[id][l][o] = bf16(W[l][o] + A[id][l][o]) ----
__global__ __launch_bounds__(256) void build_m(const float* __restrict__ W,
                                               const float* __restrict__ A,
                                               u16* __restrict__ M) {
    size_t t    = (size_t)blockIdx.x * 256 + threadIdx.x;
    size_t base = t * 4;
    float4 w = *(const float4*)(W + (base & (size_t)(NL * NO - 1)));
    float4 a = *(const float4*)(A + base);
    ushort4 m;
    m.x = f2bf(w.x + a.x); m.y = f2bf(w.y + a.y);
    m.z = f2bf(w.z + a.z); m.w = f2bf(w.w + a.w);
    *(ushort4*)(M + base) = m;
}

// ---- Pass 2: grouped GEMM -> logits. 8 rows x 512 cols per block, no barriers in loop ----
__global__ __launch_bounds__(256) void gemm_logits(
    const float* __restrict__ z, const u16* __restrict__ M,
    const float* __restrict__ offs, const int* __restrict__ perm,
    const Group* __restrict__ groups, const int* __restrict__ ngroups,
    float* __restrict__ logits)
{
    const int g  = blockIdx.x >> 2;
    const int ct = blockIdx.x & 3;
    if (g >= *ngroups) return;
    const int id     = groups[g].id;
    const int pstart = groups[g].start;
    const int nr     = groups[g].nr;
    const int tid    = threadIdx.x;

    __shared__ int   rows_s[RPB];
    __shared__ float zT[NL][RPB];

    if (tid < RPB) rows_s[tid] = perm[pstart + (tid < nr ? tid : nr - 1)];
    __syncthreads();
    {   // load zT coalesced: 512 floats, 2 per thread; lanes cover consecutive l of one row
        int r = tid >> 6, l = tid & 63;
        zT[l][r] = z[(size_t)rows_s[r] * NROW + l];
        int idx2 = tid + 256; r = idx2 >> 6; l = idx2 & 63;
        zT[l][r] = z[(size_t)rows_s[r] * NROW + l];
    }
    __syncthreads();

    const int c0 = ct * CTILE + tid * 2;
    const u16* Mg = M + (size_t)id * NL * NO + c0;

    float2 acc[RPB];
    {
        float2 o2 = *(const float2*)(offs + id * NO + c0);
        #pragma unroll
        for (int r = 0; r < RPB; ++r) acc[r] = o2;
    }

    #pragma unroll 8
    for (int l = 0; l < NL; ++l) {
        u32 m = *(const u32*)(Mg + (size_t)l * NO);   // 2 bf16, coalesced across lanes
        float ml = bflo(m), mh = bfhi(m);
        float4 za = *(const float4*)&zT[l][0];        // same-address broadcast
        float4 zb = *(const float4*)&zT[l][4];
        acc[0].x += za.x * ml; acc[0].y += za.x * mh;
        acc[1].x += za.y * ml; acc[1].y += za.y * mh;
        acc[2].x += za.z * ml; acc[2].y += za.z * mh;
        acc[3].x += za.w * ml; acc[3].y += za.w * mh;
        acc[4].x += zb.x * ml; acc[4].y += zb.x * mh;
        acc[5].x += zb.y * ml; acc[5].y += zb.y * mh;
        acc[6].x += zb.z * ml; acc[6].y += zb.z * mh;
        acc[7].x += zb.w * ml; acc[7].y += zb.w * mh;
    }

    for (int r = 0; r < nr; ++r)
        *(float2*)(logits + (size_t)rows_s[r] * NO + c0) = acc[r];
}

// ---- Pass 3: per-row softmax * size_factor -> mu ----
__global__ __launch_bounds__(256) void softmax_scale(
    const float* __restrict__ logits, const float* __restrict__ sf,
    float* __restrict__ out)
{
    const int b = blockIdx.x, tid = threadIdx.x, o0 = tid * 8;
    __shared__ float s_red[6];

    const float* lp = logits + (size_t)b * NO + o0;
    float4 v0 = *(const float4*)lp, v1 = *(const float4*)(lp + 4);
    float v[8] = { v0.x, v0.y, v0.z, v0.w, v1.x, v1.y, v1.z, v1.w };

    float m = v[0];
    #pragma unroll
    for (int j = 1; j < 8; ++j) m = fmaxf(m, v[j]);
    #pragma unroll
    for (int off = 32; off > 0; off >>= 1) m = fmaxf(m, __shfl_down(m, off));
    if ((tid & 63) == 0) s_red[tid >> 6] = m;
    __syncthreads();
    if (tid == 0) s_red[4] = fmaxf(fmaxf(s_red[0], s_red[1]), fmaxf(s_red[2], s_red[3]));
    __syncthreads();
    const float mx = s_red[4];

    float s = 0.f;
    #pragma unroll
    for (int j = 0; j < 8; ++j) { v[j] = __expf(v[j] - mx); s += v[j]; }
    #pragma unroll
    for (int off = 32; off > 0; off >>= 1) s += __shfl_down(s, off);
    if ((tid & 63) == 0) s_red[tid >> 6] = s;
    __syncthreads();
    if (tid == 0) s_red[5] = (s_red[0] + s_red[1]) + (s_red[2] + s_red[3]);
    __syncthreads();
    const float scl = sf[b] / s_red[5];

    float* op = out + (size_t)b * NO + o0;
    *(float4*)(op)     = make_float4(v[0] * scl, v[1] * scl, v[2] * scl, v[3] * scl);
    *(float4*)(op + 4) = make_float4(v[4] * scl, v[5] * scl, v[6] * scl, v[7] * scl);
}

// ---- Fallback (ws too small): round-3 row-per-block fp32 path ----
__global__ __launch_bounds__(256) void decoder_f(
    const float* __restrict__ z, const float* __restrict__ sf,
    const float* __restrict__ W, const float* __restrict__ A,
    const float* __restrict__ offs, const float* __restrict__ pxr,
    float* __restrict__ out)
{
    const int b   = blockIdx.x;
    const int tid = threadIdx.x;
    if (b == NB) {
        for (int o = tid; o < NO; o += 256) out[(size_t)NB * NO + o] = __expf(pxr[o]);
        return;
    }
    __shared__ float z0s[NL];
    __shared__ int   s_id;
    __shared__ float s_red[6];
    if (tid < NL) z0s[tid] = z[b * NROW + tid];
    if (tid == 0) {
        float best = -1e30f; int bi = 0;
        for (int i = 0; i < NN; ++i) { float v = z[b * NROW + NL + i]; if (v > best) { best = v; bi = i; } }
        s_id = bi;
    }
    __syncthreads();
    const int id = s_id;
    const int o0 = tid * 8;
    const float* wp = W + o0;
    const float* ap = A + (size_t)id * NL * NO + o0;
    float acc[8];
    {
        float4 oa = *(const float4*)(offs + id * NO + o0);
        float4 ob = *(const float4*)(offs + id * NO + o0 + 4);
        acc[0]=oa.x; acc[1]=oa.y; acc[2]=oa.z; acc[3]=oa.w;
        acc[4]=ob.x; acc[5]=ob.y; acc[6]=ob.z; acc[7]=ob.w;
    }
    #pragma unroll 4
    for (int l = 0; l < NL; ++l) {
        const float zl = z0s[l];
        float4 w0 = *(const float4*)(wp + l * NO);
        float4 w1 = *(const float4*)(wp + l * NO + 4);
        float4 a0 = *(const float4*)(ap + l * NO);
        float4 a1 = *(const float4*)(ap + l * NO + 4);
        acc[0] += zl * (w0.x + a0.x); acc[1] += zl * (w0.y + a0.y);
        acc[2] += zl * (w0.z + a0.z); acc[3] += zl * (w0.w + a0.w);
        acc[4] += zl * (w1.x + a1.x); acc[5] += zl * (w1.y + a1.y);
        acc[6] += zl * (w1.z + a1.z); acc[7] += zl * (w1.w + a1.w);
    }
    float m = acc[0];
    #pragma unroll
    for (int j = 1; j < 8; ++j) m = fmaxf(m, acc[j]);
    #pragma unroll
    for (int off = 32; off > 0; off >>= 1) m = fmaxf(m, __shfl_down(m, off));
    if ((tid & 63) == 0) s_red[tid >> 6] = m;
    __syncthreads();
    if (tid == 0) s_red[4] = fmaxf(fmaxf(s_red[0], s_red[1]), fmaxf(s_red[2], s_red[3]));
    __syncthreads();
    const float mx = s_red[4];
    float ex[8];
    float s = 0.f;
    #pragma unroll
    for (int j = 0; j < 8; ++j) { ex[j] = __expf(acc[j] - mx); s += ex[j]; }
    #pragma unroll
    for (int off = 32; off > 0; off >>= 1) s += __shfl_down(s, off);
    if ((tid & 63) == 0) s_red[tid >> 6] = s;
    __syncthreads();
    if (tid == 0) s_red[5] = (s_red[0] + s_red[1]) + (s_red[2] + s_red[3]);
    __syncthreads();
    const float scale = sf[b] / s_red[5];
    float* op = out + (size_t)b * NO + o0;
    *(float4*)(op)     = make_float4(ex[0]*scale, ex[1]*scale, ex[2]*scale, ex[3]*scale);
    *(float4*)(op + 4) = make_float4(ex[4]*scale, ex[5]*scale, ex[6]*scale, ex[7]*scale);
}

extern "C" void kernel_launch(void* const* d_in, const int* in_sizes, int n_in,
                              void* d_out, int out_size, void* d_ws, size_t ws_size,
                              hipStream_t stream) {
    const float* z    = (const float*)d_in[0];
    const float* sf   = (const float*)d_in[1];
    const float* W    = (const float*)d_in[2];
    const float* A    = (const float*)d_in[3];
    const float* offs = (const float*)d_in[4];
    const float* pxr  = (const float*)d_in[5];
    float* out = (float*)d_out;

    // ws layout: M 4MiB | perm 8KiB | groups 8KiB | ngroups 256B | logits 16MiB
    const size_t M_OFF = 0, PERM_OFF = 4u << 20, GRP_OFF = (4u << 20) + 8192,
                 NG_OFF = (4u << 20) + 16384, LG_OFF = 8u << 20;
    const size_t ws_need = LG_OFF + (size_t)NB * NO * sizeof(float);
    if (ws_size >= ws_need) {
        char* wsb = (char*)d_ws;
        u16*   M       = (u16*)(wsb + M_OFF);
        int*   perm    = (int*)(wsb + PERM_OFF);
        Group* groups  = (Group*)(wsb + GRP_OFF);
        int*   ngroups = (int*)(wsb + NG_OFF);
        float* logits  = (float*)(wsb + LG_OFF);
        hipLaunchKernelGGL(bucket_all, dim3(1), dim3(1024), 0, stream, z, pxr, perm, groups, ngroups, out);
        hipLaunchKernelGGL(build_m, dim3((NN * NL * NO / 4) / 256), dim3(256), 0, stream, W, A, M);
        hipLaunchKernelGGL(gemm_logits, dim3(MAXG * NCT), dim3(256), 0, stream,
                           z, M, offs, perm, groups, ngroups, logits);
        hipLaunchKernelGGL(softmax_scale, dim3(NB), dim3(256), 0, stream, logits, sf, out);
    } else {
        hipLaunchKernelGGL(decoder_f, dim3(NB + 1), dim3(256), 0, stream, z, sf, W, A, offs, pxr, out);
    }
}

// Round 7
// 108.834 us; speedup vs baseline: 1.4044x; 1.0889x over previous
//
#include <hip/hip_runtime.h>
#include <hip/hip_bf16.h>

#define NB 2048     // batch rows
#define NL 64       // latent dim
#define NN 16       // nuisance dim
#define NROW 80     // NL + NN
#define NO 2048     // output dim
#define RPB 8       // rows per group
#define MAXG (NB / RPB + NN)   // 272 max groups

typedef unsigned int   u32;
typedef unsigned short u16;

struct Group { int id; int start; int nr; int pad; };

__device__ __forceinline__ float bflo(u32 u) { union { u32 i; float f; } c; c.i = u << 16;         return c.f; }
__device__ __forceinline__ float bfhi(u32 u) { union { u32 i; float f; } c; c.i = u & 0xffff0000u; return c.f; }
__device__ __forceinline__ u16 f2bf(float f) { __hip_bfloat16 h = __float2bfloat16(f); return *(u16*)&h; }

// ---- Pass 0+1 fused: block 0 buckets rows + theta; blocks 1..1024 build M ----
// M[id][l][o] = bf16(W[l][o] + A[id][l][o])
__global__ __launch_bounds__(512) void prep(
    const float* __restrict__ z, const float* __restrict__ pxr,
    const float* __restrict__ W, const float* __restrict__ A,
    u16* __restrict__ M, int* __restrict__ perm, Group* __restrict__ groups,
    int* __restrict__ ngroups, float* __restrict__ out)
{
    const int tid = threadIdx.x;

    if (blockIdx.x != 0) {               // ---- builder blocks ----
        size_t i = ((size_t)(blockIdx.x - 1) * 512 + tid) * 4;
        float4 w = *(const float4*)(W + (i & (size_t)(NL * NO - 1)));
        float4 a = *(const float4*)(A + i);
        ushort4 m;
        m.x = f2bf(w.x + a.x); m.y = f2bf(w.y + a.y);
        m.z = f2bf(w.z + a.z); m.w = f2bf(w.w + a.w);
        *(ushort4*)(M + i) = m;
        return;
    }

    // ---- bucket block ----
    __shared__ int cnt[NN], start_s[NN], cur[NN], gbase_s[NN];
    __shared__ int ids_sh[NB];           // 8 KB

    if (tid < NN) cnt[tid] = 0;
    for (int o = tid; o < NO; o += 512)  // theta = exp(px_r)
        out[(size_t)NB * NO + o] = __expf(pxr[o]);
    __syncthreads();

    // argmax ids: 4 lanes per row, each reads one aligned float4 of the 16 nuisance floats
    const int c = tid & 3;
    #pragma unroll 4
    for (int pass = 0; pass < 16; ++pass) {
        const int row = pass * 128 + (tid >> 2);
        float4 v = *(const float4*)(z + (size_t)row * NROW + NL + c * 4);
        float bv = v.x; int bp = c * 4;
        if (v.y > bv) { bv = v.y; bp = c * 4 + 1; }
        if (v.z > bv) { bv = v.z; bp = c * 4 + 2; }
        if (v.w > bv) { bv = v.w; bp = c * 4 + 3; }
        #pragma unroll
        for (int d = 1; d <= 2; d <<= 1) {          // combine 4 lanes, first-max tie-break
            float ov = __shfl_xor(bv, d);
            int   op = __shfl_xor(bp, d);
            if (ov > bv || (ov == bv && op < bp)) { bv = ov; bp = op; }
        }
        if (c == 0) { ids_sh[row] = bp; atomicAdd(&cnt[bp], 1); }
    }
    __syncthreads();

    if (tid == 0) {                       // prefix + group bases
        int acc = 0, g = 0;
        for (int i = 0; i < NN; ++i) {
            start_s[i] = acc; cur[i] = acc; gbase_s[i] = g;
            acc += cnt[i]; g += (cnt[i] + RPB - 1) / RPB;
        }
        *ngroups = g;
    }
    __syncthreads();

    #pragma unroll
    for (int k = 0; k < NB / 512; ++k) {  // scatter perm (order within bucket arbitrary)
        const int row = tid + k * 512;
        const int id  = ids_sh[row];
        const int pos = atomicAdd(&cur[id], 1);
        perm[pos] = row;
    }
    if (tid < NN) {                       // group table
        const int cn = cnt[tid], s = start_s[tid], gb = gbase_s[tid];
        for (int j = 0; j * RPB < cn; ++j) {
            Group gr; gr.id = tid; gr.start = s + j * RPB;
            gr.nr = min(RPB, cn - j * RPB); gr.pad = 0;
            groups[gb + j] = gr;
        }
    }
}

// ---- Pass 2: fused grouped GEMM + softmax. 8 rows x 2048 cols per block ----
__global__ __launch_bounds__(512, 2) void gemm_fused(
    const float* __restrict__ z, const float* __restrict__ sf,
    const u16* __restrict__ M, const float* __restrict__ offs,
    const int* __restrict__ perm, const Group* __restrict__ groups,
    const int* __restrict__ ngroups, float* __restrict__ out)
{
    const int g = blockIdx.x;
    if (g >= *ngroups) return;
    const int id     = groups[g].id;
    const int pstart = groups[g].start;
    const int nr     = groups[g].nr;
    const int tid    = threadIdx.x;
    const int lane   = tid & 63, wave = tid >> 6;   // 8 waves

    __shared__ int   rows_s[RPB];
    __shared__ float zT[NL][RPB];
    __shared__ float sfs[RPB];
    __shared__ float red[8][RPB];
    __shared__ float gmax[RPB], gsum[RPB];

    if (tid < RPB) rows_s[tid] = perm[pstart + (tid < nr ? tid : nr - 1)];
    __syncthreads();
    {   // zT: 512 floats, one per thread; lanes cover consecutive l of one row (coalesced)
        const int r = tid >> 6, l = tid & 63;
        zT[l][r] = z[(size_t)rows_s[r] * NROW + l];
    }
    if (tid < RPB) sfs[tid] = sf[rows_s[tid]];
    __syncthreads();

    const int c0 = tid * 4;
    const u16* Mg = M + (size_t)id * NL * NO + c0;

    float acc[RPB][4];
    {
        float4 o4 = *(const float4*)(offs + id * NO + c0);
        #pragma unroll
        for (int r = 0; r < RPB; ++r) {
            acc[r][0] = o4.x; acc[r][1] = o4.y; acc[r][2] = o4.z; acc[r][3] = o4.w;
        }
    }

    #pragma unroll 8
    for (int l = 0; l < NL; ++l) {
        uint2 m = *(const uint2*)(Mg + (size_t)l * NO);   // 4 bf16, coalesced
        float m0 = bflo(m.x), m1 = bfhi(m.x), m2 = bflo(m.y), m3 = bfhi(m.y);
        float4 za = *(const float4*)&zT[l][0];            // LDS broadcast
        float4 zb = *(const float4*)&zT[l][4];
        acc[0][0] += za.x * m0; acc[0][1] += za.x * m1; acc[0][2] += za.x * m2; acc[0][3] += za.x * m3;
        acc[1][0] += za.y * m0; acc[1][1] += za.y * m1; acc[1][2] += za.y * m2; acc[1][3] += za.y * m3;
        acc[2][0] += za.z * m0; acc[2][1] += za.z * m1; acc[2][2] += za.z * m2; acc[2][3] += za.z * m3;
        acc[3][0] += za.w * m0; acc[3][1] += za.w * m1; acc[3][2] += za.w * m2; acc[3][3] += za.w * m3;
        acc[4][0] += zb.x * m0; acc[4][1] += zb.x * m1; acc[4][2] += zb.x * m2; acc[4][3] += zb.x * m3;
        acc[5][0] += zb.y * m0; acc[5][1] += zb.y * m1; acc[5][2] += zb.y * m2; acc[5][3] += zb.y * m3;
        acc[6][0] += zb.z * m0; acc[6][1] += zb.z * m1; acc[6][2] += zb.z * m2; acc[6][3] += zb.z * m3;
        acc[7][0] += zb.w * m0; acc[7][1] += zb.w * m1; acc[7][2] += zb.w * m2; acc[7][3] += zb.w * m3;
    }

    // ---- block max per row ----
    float rv[RPB];
    #pragma unroll
    for (int r = 0; r < RPB; ++r) {
        float mv = fmaxf(fmaxf(acc[r][0], acc[r][1]), fmaxf(acc[r][2], acc[r][3]));
        #pragma unroll
        for (int off = 32; off > 0; off >>= 1) mv = fmaxf(mv, __shfl_down(mv, off));
        rv[r] = mv;
    }
    if (lane == 0) {
        for (int r = 0; r < RPB; ++r) red[wave][r] = rv[r];
    }
    __syncthreads();
    if (tid < RPB) {
        float mm = red[0][tid];
        #pragma unroll
        for (int w = 1; w < 8; ++w) mm = fmaxf(mm, red[w][tid]);
        gmax[tid] = mm;
    }
    __syncthreads();

    // ---- exp + block sum per row ----
    #pragma unroll
    for (int r = 0; r < RPB; ++r) {
        const float mx = gmax[r];
        float s = 0.f;
        #pragma unroll
        for (int cc = 0; cc < 4; ++cc) { acc[r][cc] = __expf(acc[r][cc] - mx); s += acc[r][cc]; }
        #pragma unroll
        for (int off = 32; off > 0; off >>= 1) s += __shfl_down(s, off);
        rv[r] = s;
    }
    if (lane == 0) {
        for (int r = 0; r < RPB; ++r) red[wave][r] = rv[r];
    }
    __syncthreads();
    if (tid < RPB) {
        float ss = 0.f;
        #pragma unroll
        for (int w = 0; w < 8; ++w) ss += red[w][tid];
        gsum[tid] = ss;
    }
    __syncthreads();

    for (int r = 0; r < nr; ++r) {
        const float scl = sfs[r] / gsum[r];
        *(float4*)(out + (size_t)rows_s[r] * NO + c0) =
            make_float4(acc[r][0] * scl, acc[r][1] * scl, acc[r][2] * scl, acc[r][3] * scl);
    }
}

// ---- Fallback (ws too small): row-per-block fp32 path ----
__global__ __launch_bounds__(256) void decoder_f(
    const float* __restrict__ z, const float* __restrict__ sf,
    const float* __restrict__ W, const float* __restrict__ A,
    const float* __restrict__ offs, const float* __restrict__ pxr,
    float* __restrict__ out)
{
    const int b   = blockIdx.x;
    const int tid = threadIdx.x;
    if (b == NB) {
        for (int o = tid; o < NO; o += 256) out[(size_t)NB * NO + o] = __expf(pxr[o]);
        return;
    }
    __shared__ float z0s[NL];
    __shared__ int   s_id;
    __shared__ float s_red[6];
    if (tid < NL) z0s[tid] = z[b * NROW + tid];
    if (tid == 0) {
        float best = -1e30f; int bi = 0;
        for (int i = 0; i < NN; ++i) { float v = z[b * NROW + NL + i]; if (v > best) { best = v; bi = i; } }
        s_id = bi;
    }
    __syncthreads();
    const int id = s_id;
    const int o0 = tid * 8;
    const float* wp = W + o0;
    const float* ap = A + (size_t)id * NL * NO + o0;
    float acc[8];
    {
        float4 oa = *(const float4*)(offs + id * NO + o0);
        float4 ob = *(const float4*)(offs + id * NO + o0 + 4);
        acc[0]=oa.x; acc[1]=oa.y; acc[2]=oa.z; acc[3]=oa.w;
        acc[4]=ob.x; acc[5]=ob.y; acc[6]=ob.z; acc[7]=ob.w;
    }
    #pragma unroll 4
    for (int l = 0; l < NL; ++l) {
        const float zl = z0s[l];
        float4 w0 = *(const float4*)(wp + l * NO);
        float4 w1 = *(const float4*)(wp + l * NO + 4);
        float4 a0 = *(const float4*)(ap + l * NO);
        float4 a1 = *(const float4*)(ap + l * NO + 4);
        acc[0] += zl * (w0.x + a0.x); acc[1] += zl * (w0.y + a0.y);
        acc[2] += zl * (w0.z + a0.z); acc[3] += zl * (w0.w + a0.w);
        acc[4] += zl * (w1.x + a1.x); acc[5] += zl * (w1.y + a1.y);
        acc[6] += zl * (w1.z + a1.z); acc[7] += zl * (w1.w + a1.w);
    }
    float m = acc[0];
    #pragma unroll
    for (int j = 1; j < 8; ++j) m = fmaxf(m, acc[j]);
    #pragma unroll
    for (int off = 32; off > 0; off >>= 1) m = fmaxf(m, __shfl_down(m, off));
    if ((tid & 63) == 0) s_red[tid >> 6] = m;
    __syncthreads();
    if (tid == 0) s_red[4] = fmaxf(fmaxf(s_red[0], s_red[1]), fmaxf(s_red[2], s_red[3]));
    __syncthreads();
    const float mx = s_red[4];
    float ex[8];
    float s = 0.f;
    #pragma unroll
    for (int j = 0; j < 8; ++j) { ex[j] = __expf(acc[j] - mx); s += ex[j]; }
    #pragma unroll
    for (int off = 32; off > 0; off >>= 1) s += __shfl_down(s, off);
    if ((tid & 63) == 0) s_red[tid >> 6] = s;
    __syncthreads();
    if (tid == 0) s_red[5] = (s_red[0] + s_red[1]) + (s_red[2] + s_red[3]);
    __syncthreads();
    const float scale = sf[b] / s_red[5];
    float* op = out + (size_t)b * NO + o0;
    *(float4*)(op)     = make_float4(ex[0]*scale, ex[1]*scale, ex[2]*scale, ex[3]*scale);
    *(float4*)(op + 4) = make_float4(ex[4]*scale, ex[5]*scale, ex[6]*scale, ex[7]*scale);
}

extern "C" void kernel_launch(void* const* d_in, const int* in_sizes, int n_in,
                              void* d_out, int out_size, void* d_ws, size_t ws_size,
                              hipStream_t stream) {
    const float* z    = (const float*)d_in[0];
    const float* sf   = (const float*)d_in[1];
    const float* W    = (const float*)d_in[2];
    const float* A    = (const float*)d_in[3];
    const float* offs = (const float*)d_in[4];
    const float* pxr  = (const float*)d_in[5];
    float* out = (float*)d_out;

    // ws layout: M 4MiB | perm 8KiB | groups 8KiB | ngroups
    const size_t M_OFF = 0, PERM_OFF = 4u << 20, GRP_OFF = (4u << 20) + 8192,
                 NG_OFF = (4u << 20) + 16384;
    const size_t ws_need = NG_OFF + 256;
    if (ws_size >= ws_need) {
        char* wsb = (char*)d_ws;
        u16*   M       = (u16*)(wsb + M_OFF);
        int*   perm    = (int*)(wsb + PERM_OFF);
        Group* groups  = (Group*)(wsb + GRP_OFF);
        int*   ngroups = (int*)(wsb + NG_OFF);
        // grid: block 0 buckets, blocks 1..1024 build M (2M elems / (512 thr * 4))
        hipLaunchKernelGGL(prep, dim3(1 + (NN * NL * NO / 4) / 512), dim3(512), 0, stream,
                           z, pxr, W, A, M, perm, groups, ngroups, out);
        hipLaunchKernelGGL(gemm_fused, dim3(MAXG), dim3(512), 0, stream,
                           z, sf, M, offs, perm, groups, ngroups, out);
    } else {
        hipLaunchKernelGGL(decoder_f, dim3(NB + 1), dim3(256), 0, stream, z, sf, W, A, offs, pxr, out);
    }
}